// Round 1
// baseline (269.248 us; speedup 1.0000x reference)
//
#include <hip/hip_runtime.h>

// Problem constants (B=2, N=768, D_IN=D_OUT=64, TEMP=2, BN_EPS=1e-5)
constexpr int Bc = 2;
constexpr int Nc = 768;
constexpr int Dc = 64;
constexpr int CHUNK = 128;            // j-rows staged per LDS chunk (32 KB)
constexpr int WAVES = 4;              // 256 threads
constexpr int JPW = CHUNK / WAVES;    // 32 j's per wave per chunk

__global__ __launch_bounds__(256, 4)
void ensemble_kernel(const float* __restrict__ x,
                     const float* __restrict__ W_att,
                     const float* __restrict__ b_att,
                     const float* __restrict__ a_w,
                     const float* __restrict__ W_p,
                     const float* __restrict__ b_p,
                     const float* __restrict__ W_q,
                     const float* __restrict__ b_q,
                     const float* __restrict__ gamma,
                     const float* __restrict__ beta,
                     const float* __restrict__ r_mean,
                     const float* __restrict__ r_var,
                     float* __restrict__ out)
{
    __shared__ float s_x[CHUNK][Dc];   // staged x[b] chunk: 32 KB
    __shared__ float s_score[Nc];      // scores then att: 3 KB
    __shared__ float s_xi[Dc];         // x[b,i,:]
    __shared__ float s_red[WAVES][Dc]; // agg partials / final agg
    __shared__ float s_tmp[WAVES];     // block-reduce scratch

    const int bid = blockIdx.x;        // b*N + i
    const int b   = bid / Nc;
    const int i   = bid - b * Nc;
    const int tid  = threadIdx.x;
    const int lane = tid & 63;         // = output channel o
    const int wid  = tid >> 6;

    const float* xb = x + (size_t)b * Nc * Dc;

    if (tid < Dc) s_xi[tid] = xb[i * Dc + tid];
    __syncthreads();

    // Per-lane column of M_i[d,o] = x_i[d] * W_att[d,o]; W_att reads coalesced over o.
    float mcol[Dc];
#pragma unroll
    for (int d = 0; d < Dc; ++d)
        mcol[d] = s_xi[d] * W_att[d * Dc + lane];
    const float aw = a_w[lane];
    const float ba = b_att[lane];

    // ---- scores[j] = dot(tanh(x_j @ M_i + b_att), a_w) / TEMP ----
    for (int c = 0; c < Nc / CHUNK; ++c) {
        __syncthreads();
        // stage 128 rows of x[b] (8192 floats) with 256 threads x 8 float4
        const float4* src = (const float4*)(xb + c * CHUNK * Dc);
        float4* dst = (float4*)(&s_x[0][0]);
#pragma unroll
        for (int k = 0; k < (CHUNK * Dc / 4) / 256; ++k)
            dst[tid + k * 256] = src[tid + k * 256];
        __syncthreads();

        for (int jj = 0; jj < JPW; ++jj) {
            const int jl = wid * JPW + jj;
            float t = ba;
#pragma unroll
            for (int d = 0; d < Dc; d += 4) {
                const float4 xv = *(const float4*)(&s_x[jl][d]);  // uniform addr: LDS broadcast
                t = fmaf(xv.x, mcol[d + 0], t);
                t = fmaf(xv.y, mcol[d + 1], t);
                t = fmaf(xv.z, mcol[d + 2], t);
                t = fmaf(xv.w, mcol[d + 3], t);
            }
            // fast tanh via v_exp; clamp to avoid inf/inf
            t = fminf(fmaxf(t, -15.f), 15.f);
            const float e  = __expf(2.f * t);
            const float th = (e - 1.f) / (e + 1.f);
            float p = th * aw;
#pragma unroll
            for (int off = 32; off; off >>= 1)
                p += __shfl_xor(p, off, 64);
            if (lane == 0)
                s_score[c * CHUNK + jl] = p * 0.5f;  // / TEMP
        }
    }
    __syncthreads();

    // ---- softmax over j (768 values) ----
    float mx = -1e30f;
    for (int j = tid; j < Nc; j += 256) mx = fmaxf(mx, s_score[j]);
#pragma unroll
    for (int off = 32; off; off >>= 1)
        mx = fmaxf(mx, __shfl_xor(mx, off, 64));
    if (lane == 0) s_tmp[wid] = mx;
    __syncthreads();
    mx = fmaxf(fmaxf(s_tmp[0], s_tmp[1]), fmaxf(s_tmp[2], s_tmp[3]));
    __syncthreads();  // s_tmp reused below

    float sm = 0.f;
    for (int j = tid; j < Nc; j += 256) {
        const float e = __expf(s_score[j] - mx);
        s_score[j] = e;   // own slots only; no race
        sm += e;
    }
#pragma unroll
    for (int off = 32; off; off >>= 1)
        sm += __shfl_xor(sm, off, 64);
    if (lane == 0) s_tmp[wid] = sm;
    __syncthreads();
    const float inv_sum = 1.f / (s_tmp[0] + s_tmp[1] + s_tmp[2] + s_tmp[3]);

    // ---- agg[d] = sum_j att[j] * x[b,j,d] ; lane = d ----
    float aggp = 0.f;
    const int j0 = wid * (Nc / WAVES), j1 = j0 + Nc / WAVES;
    for (int j = j0; j < j1; ++j)
        aggp = fmaf(s_score[j], xb[j * Dc + lane], aggp);  // coalesced, L2-hit
    s_red[wid][lane] = aggp;
    __syncthreads();

    if (wid == 0)
        s_red[0][lane] = (s_red[0][lane] + s_red[1][lane] +
                          s_red[2][lane] + s_red[3][lane]) * inv_sum;
    __syncthreads();

    // ---- epilogue: y = agg@W_p + b_p + x_i@W_q + b_q; BN(eval); SELU ----
    if (wid == 0) {
        float y = b_p[lane] + b_q[lane];
#pragma unroll 8
        for (int d = 0; d < Dc; ++d) {
            y = fmaf(s_red[0][d], W_p[d * Dc + lane], y);
            y = fmaf(s_xi[d],     W_q[d * Dc + lane], y);
        }
        const float inv_std = rsqrtf(r_var[lane] + 1e-5f);
        y = (y - r_mean[lane]) * (gamma[lane] * inv_std) + beta[lane];
        const float kScale = 1.0507009873554805f;
        const float kAlpha = 1.6732632423543772f;
        y = y > 0.f ? kScale * y : kScale * kAlpha * (__expf(y) - 1.f);
        out[bid * Dc + lane] = y;
    }
}

extern "C" void kernel_launch(void* const* d_in, const int* in_sizes, int n_in,
                              void* d_out, int out_size, void* d_ws, size_t ws_size,
                              hipStream_t stream) {
    const float* x      = (const float*)d_in[0];
    const float* W_att  = (const float*)d_in[1];
    const float* b_att  = (const float*)d_in[2];
    const float* a_w    = (const float*)d_in[3];
    const float* W_p    = (const float*)d_in[4];
    const float* b_p    = (const float*)d_in[5];
    const float* W_q    = (const float*)d_in[6];
    const float* b_q    = (const float*)d_in[7];
    const float* gamma  = (const float*)d_in[8];
    const float* beta   = (const float*)d_in[9];
    const float* r_mean = (const float*)d_in[10];
    const float* r_var  = (const float*)d_in[11];
    float* out = (float*)d_out;

    ensemble_kernel<<<dim3(Bc * Nc), dim3(256), 0, stream>>>(
        x, W_att, b_att, a_w, W_p, b_p, W_q, b_q,
        gamma, beta, r_mean, r_var, out);
}

// Round 2
// 55.735 us; speedup vs baseline: 4.8308x; 4.8308x over previous
//
#include <hip/hip_runtime.h>
#include <hip/hip_bf16.h>

// B=2, N=768, D_IN=D_OUT=64, TEMP=2, BN_EPS=1e-5
constexpr int Bc = 2;
constexpr int Nc = 768;
constexpr int Dc = 64;

typedef __attribute__((ext_vector_type(8))) short short8;   // 8 bf16 (4 VGPRs) — MFMA A/B frag
typedef __attribute__((ext_vector_type(4))) float f32x4;    // MFMA C/D frag

__device__ inline short fbf(float f) {
    __hip_bfloat16 h = __float2bfloat16(f);
    return *reinterpret_cast<short*>(&h);
}

__device__ inline short8 pack8(float4 a, float4 b) {
    short8 r;
    r[0] = fbf(a.x); r[1] = fbf(a.y); r[2] = fbf(a.z); r[3] = fbf(a.w);
    r[4] = fbf(b.x); r[5] = fbf(b.y); r[6] = fbf(b.z); r[7] = fbf(b.w);
    return r;
}

__global__ __launch_bounds__(256, 4)
void ensemble_kernel(const float* __restrict__ x,
                     const float* __restrict__ W_att,
                     const float* __restrict__ b_att,
                     const float* __restrict__ a_w,
                     const float* __restrict__ W_p,
                     const float* __restrict__ b_p,
                     const float* __restrict__ W_q,
                     const float* __restrict__ b_q,
                     const float* __restrict__ gamma,
                     const float* __restrict__ beta,
                     const float* __restrict__ r_mean,
                     const float* __restrict__ r_var,
                     float* __restrict__ out)
{
    // A = M_i^T[o][d] = x_i[d]*W_att[d][o], bf16. Row o = 128 B; stored as 8
    // chunks of 16 B with chunk XOR-swizzle (phys = c ^ (o&7)) so the MFMA
    // A-frag ds_read_b128 (16 lanes, same chunk, rows 0..15) is conflict-free.
    __shared__ short s_A[Dc * Dc];     // 8 KB
    __shared__ float s_score[Nc];      // 3 KB
    __shared__ float s_xi[Dc];
    __shared__ float s_red[4][Dc];
    __shared__ float s_tmp[4];

    const int bid = blockIdx.x;        // b*N + i
    const int b   = bid / Nc;
    const int i   = bid - b * Nc;
    const int tid  = threadIdx.x;
    const int lane = tid & 63;
    const int wid  = tid >> 6;

    const float* xb = x + (size_t)b * Nc * Dc;

    if (tid < Dc) s_xi[tid] = xb[i * Dc + tid];
    __syncthreads();

    // ---- build swizzled A in LDS: wave w covers d in [16w, 16w+16), lane = o ----
    {
        const int d0 = wid * 16;
        float m0[16];
#pragma unroll
        for (int dd = 0; dd < 16; ++dd)
            m0[dd] = s_xi[d0 + dd] * W_att[(d0 + dd) * Dc + lane];  // coalesced over o
#pragma unroll
        for (int c8 = 0; c8 < 2; ++c8) {
            short8 v;
#pragma unroll
            for (int e = 0; e < 8; ++e) v[e] = fbf(m0[c8 * 8 + e]);
            const int c    = wid * 2 + c8;
            const int phys = c ^ (lane & 7);
            *(short8*)(&s_A[lane * Dc + phys * 8]) = v;
        }
    }

    // per-lane score constants: this lane's 16 o's are 16*mt + 4*(lane>>4) + r
    float tb[16], aw[16];
#pragma unroll
    for (int mt = 0; mt < 4; ++mt)
#pragma unroll
        for (int r = 0; r < 4; ++r) {
            const int o = 16 * mt + 4 * (lane >> 4) + r;
            tb[mt * 4 + r] = 2.f * b_att[o];
            aw[mt * 4 + r] = a_w[o];
        }
    __syncthreads();

    // ---- preload loop-invariant A-frags (o = M dim, d = K dim) ----
    // A-frag layout: lane = 16*(k/8) + m, elems k%8  =>  m = lane&15, k = 8*(lane>>4)+e
    short8 afr[4][2];
#pragma unroll
    for (int mt = 0; mt < 4; ++mt)
#pragma unroll
        for (int kt = 0; kt < 2; ++kt) {
            const int o    = 16 * mt + (lane & 15);
            const int c    = (lane >> 4) + 4 * kt;
            const int phys = c ^ (o & 7);
            afr[mt][kt] = *(const short8*)(&s_A[o * Dc + phys * 8]);
        }

    // ---- main loop: t^T[o][j] = A @ x^T, 12 j-tiles of 16 per wave ----
    const int jbase = wid * 192;
    for (int t = 0; t < 12; ++t) {
        const int j0 = jbase + t * 16;
        // B-frag: lane = 16*(k/8) + n  =>  j = j0 + (lane&15), d = 8*(lane>>4)+e (+32 for kt1)
        const float* xr = xb + (size_t)(j0 + (lane & 15)) * Dc + (lane >> 4) * 8;
        const float4 v0 = *(const float4*)(xr);
        const float4 v1 = *(const float4*)(xr + 4);
        const float4 v2 = *(const float4*)(xr + 32);
        const float4 v3 = *(const float4*)(xr + 36);
        const short8 bf0 = pack8(v0, v1);
        const short8 bf1 = pack8(v2, v3);

        f32x4 ac[4];
#pragma unroll
        for (int mt = 0; mt < 4; ++mt) {
            ac[mt] = (f32x4){0.f, 0.f, 0.f, 0.f};
            ac[mt] = __builtin_amdgcn_mfma_f32_16x16x32_bf16(afr[mt][0], bf0, ac[mt], 0, 0, 0);
            ac[mt] = __builtin_amdgcn_mfma_f32_16x16x32_bf16(afr[mt][1], bf1, ac[mt], 0, 0, 0);
        }

        // score[j] = sum_o tanh(t + b_att[o]) * a_w[o];  tanh(u) = 1 - 2/(e^{2u}+1)
        float p = 0.f;
#pragma unroll
        for (int mt = 0; mt < 4; ++mt)
#pragma unroll
            for (int r = 0; r < 4; ++r) {
                const float e  = __expf(fmaf(ac[mt][r], 2.f, tb[mt * 4 + r]));
                const float th = 1.f - 2.f * __builtin_amdgcn_rcpf(e + 1.f);
                p = fmaf(th, aw[mt * 4 + r], p);
            }
        p += __shfl_xor(p, 16, 64);
        p += __shfl_xor(p, 32, 64);
        if (lane < 16) s_score[j0 + lane] = p * 0.5f;   // /TEMP
    }
    __syncthreads();

    // ---- softmax over j (768 values) ----
    float mx = -1e30f;
    for (int j = tid; j < Nc; j += 256) mx = fmaxf(mx, s_score[j]);
#pragma unroll
    for (int off = 32; off; off >>= 1)
        mx = fmaxf(mx, __shfl_xor(mx, off, 64));
    if (lane == 0) s_tmp[wid] = mx;
    __syncthreads();
    mx = fmaxf(fmaxf(s_tmp[0], s_tmp[1]), fmaxf(s_tmp[2], s_tmp[3]));
    __syncthreads();

    float sm = 0.f;
    for (int j = tid; j < Nc; j += 256) {
        const float e = __expf(s_score[j] - mx);
        s_score[j] = e;
        sm += e;
    }
#pragma unroll
    for (int off = 32; off; off >>= 1)
        sm += __shfl_xor(sm, off, 64);
    if (lane == 0) s_tmp[wid] = sm;
    __syncthreads();
    const float inv_sum = 1.f / (s_tmp[0] + s_tmp[1] + s_tmp[2] + s_tmp[3]);

    // ---- agg[d] = sum_j att[j] * x[b,j,d] ; lane = d ----
    float aggp = 0.f;
    const int j0 = wid * (Nc / 4), j1 = j0 + Nc / 4;
    for (int j = j0; j < j1; ++j)
        aggp = fmaf(s_score[j], xb[j * Dc + lane], aggp);
    s_red[wid][lane] = aggp;
    __syncthreads();

    if (wid == 0)
        s_red[0][lane] = (s_red[0][lane] + s_red[1][lane] +
                          s_red[2][lane] + s_red[3][lane]) * inv_sum;
    __syncthreads();

    // ---- epilogue: proj + BN(eval) + SELU ----
    if (wid == 0) {
        float y = b_p[lane] + b_q[lane];
#pragma unroll 8
        for (int d = 0; d < Dc; ++d) {
            y = fmaf(s_red[0][d], W_p[d * Dc + lane], y);
            y = fmaf(s_xi[d],     W_q[d * Dc + lane], y);
        }
        const float inv_std = rsqrtf(r_var[lane] + 1e-5f);
        y = (y - r_mean[lane]) * (gamma[lane] * inv_std) + beta[lane];
        const float kScale = 1.0507009873554805f;
        const float kAlpha = 1.6732632423543772f;
        y = y > 0.f ? kScale * y : kScale * kAlpha * (__expf(y) - 1.f);
        out[bid * Dc + lane] = y;
    }
}

extern "C" void kernel_launch(void* const* d_in, const int* in_sizes, int n_in,
                              void* d_out, int out_size, void* d_ws, size_t ws_size,
                              hipStream_t stream) {
    const float* x      = (const float*)d_in[0];
    const float* W_att  = (const float*)d_in[1];
    const float* b_att  = (const float*)d_in[2];
    const float* a_w    = (const float*)d_in[3];
    const float* W_p    = (const float*)d_in[4];
    const float* b_p    = (const float*)d_in[5];
    const float* W_q    = (const float*)d_in[6];
    const float* b_q    = (const float*)d_in[7];
    const float* gamma  = (const float*)d_in[8];
    const float* beta   = (const float*)d_in[9];
    const float* r_mean = (const float*)d_in[10];
    const float* r_var  = (const float*)d_in[11];
    float* out = (float*)d_out;

    ensemble_kernel<<<dim3(Bc * Nc), dim3(256), 0, stream>>>(
        x, W_att, b_att, a_w, W_p, b_p, W_q, b_q,
        gamma, beta, r_mean, r_var, out);
}

// Round 3
// 43.241 us; speedup vs baseline: 6.2266x; 1.2889x over previous
//
#include <hip/hip_runtime.h>
#include <hip/hip_bf16.h>

// B=2, N=768, D_IN=D_OUT=64, TEMP=2, BN_EPS=1e-5
constexpr int Bc = 2;
constexpr int Nc = 768;
constexpr int Dc = 64;

typedef __attribute__((ext_vector_type(8))) short short8;   // 8 bf16 (4 VGPRs)
typedef __attribute__((ext_vector_type(4))) short short4v;  // 4 bf16
typedef __attribute__((ext_vector_type(4))) float f32x4;    // MFMA C/D frag

// 2*log2(e): tanh(u) = 1 - 2*rcp(exp2(u*2log2e)+1)
#define TWO_LOG2E 2.8853900817779268f

__device__ inline short fbf(float f) {
    __hip_bfloat16 h = __float2bfloat16(f);
    return *reinterpret_cast<short*>(&h);
}

// ---------------- prep: x f32 -> bf16 into ws ----------------
__global__ __launch_bounds__(256)
void prep_kernel(const float* __restrict__ x, short* __restrict__ xb)
{
    const int idx = blockIdx.x * 256 + threadIdx.x;   // 24576 float4s
    const float4 v = ((const float4*)x)[idx];
    short4v o;
    o[0] = fbf(v.x); o[1] = fbf(v.y); o[2] = fbf(v.z); o[3] = fbf(v.w);
    ((short4v*)xb)[idx] = o;
}

// ---------------- scores: s[b,i,j] for j >= i (symmetric) ----------------
__global__ __launch_bounds__(256, 4)
void scores_kernel(const float* __restrict__ x,
                   const short* __restrict__ xbf,
                   const float* __restrict__ W_att,
                   const float* __restrict__ b_att,
                   const float* __restrict__ a_w,
                   float* __restrict__ sc)
{
    __shared__ short s_A[Dc * Dc];     // swizzled A = M_i^T, bf16, 8 KB
    __shared__ float s_xi[Dc];

    const int blk = blockIdx.x;        // interleave b so heavy (low-i) blocks go first
    const int b   = blk & 1;
    const int i   = blk >> 1;
    const int tid  = threadIdx.x;
    const int lane = tid & 63;
    const int wid  = tid >> 6;

    const float* xb  = x   + (size_t)b * Nc * Dc;
    const short* xbb = xbf + (size_t)b * Nc * Dc;

    if (tid < Dc) s_xi[tid] = xb[i * Dc + tid];
    __syncthreads();

    // build swizzled A in LDS: A[o][d] = x_i[d]*W_att[d][o]; chunk phys = c ^ (o&7)
    {
        const int d0 = wid * 16;
        float m0[16];
#pragma unroll
        for (int dd = 0; dd < 16; ++dd)
            m0[dd] = s_xi[d0 + dd] * W_att[(d0 + dd) * Dc + lane];
#pragma unroll
        for (int c8 = 0; c8 < 2; ++c8) {
            short8 v;
#pragma unroll
            for (int e = 0; e < 8; ++e) v[e] = fbf(m0[c8 * 8 + e]);
            const int c    = wid * 2 + c8;
            const int phys = c ^ (lane & 7);
            *(short8*)(&s_A[lane * Dc + phys * 8]) = v;
        }
    }

    // per-lane constants for the 16 o's this lane accumulates (o = 16*mt + 4*(lane>>4) + r)
    float tb2[16], aw[16];
#pragma unroll
    for (int mt = 0; mt < 4; ++mt)
#pragma unroll
        for (int r = 0; r < 4; ++r) {
            const int o = 16 * mt + 4 * (lane >> 4) + r;
            tb2[mt * 4 + r] = TWO_LOG2E * b_att[o];
            aw [mt * 4 + r] = a_w[o];
        }
    // 0.5 * sum(a_w) via own-16 + cross-lane combine
    float sa = 0.f;
#pragma unroll
    for (int k = 0; k < 16; ++k) sa += aw[k];
    sa += __shfl_xor(sa, 16, 64);
    sa += __shfl_xor(sa, 32, 64);
    const float half_sum_aw = 0.5f * sa;
    __syncthreads();

    // preload loop-invariant A-frags
    short8 afr[4][2];
#pragma unroll
    for (int mt = 0; mt < 4; ++mt)
#pragma unroll
        for (int kt = 0; kt < 2; ++kt) {
            const int o    = 16 * mt + (lane & 15);
            const int c    = (lane >> 4) + 4 * kt;
            const int phys = c ^ (o & 7);
            afr[mt][kt] = *(const short8*)(&s_A[o * Dc + phys * 8]);
        }

    float* srow = sc + ((size_t)b * Nc + i) * Nc;
    const int t0 = i >> 4;             // first tile containing j >= i

    int t = t0 + wid;                  // waves round-robin tiles
    if (t < 48) {
        // 1-deep prefetch of B-frags (bf16 x rows straight from ws)
        const short* p0 = xbb + (size_t)(16 * t + (lane & 15)) * Dc + (lane >> 4) * 8;
        short8 c0 = *(const short8*)p0;
        short8 c1 = *(const short8*)(p0 + 32);
        while (t < 48) {
            const int tn = t + 4;
            short8 n0, n1;
            if (tn < 48) {
                const short* p1 = xbb + (size_t)(16 * tn + (lane & 15)) * Dc + (lane >> 4) * 8;
                n0 = *(const short8*)p1;
                n1 = *(const short8*)(p1 + 32);
            }

            f32x4 ac[4];
#pragma unroll
            for (int mt = 0; mt < 4; ++mt) {
                ac[mt] = (f32x4){0.f, 0.f, 0.f, 0.f};
                ac[mt] = __builtin_amdgcn_mfma_f32_16x16x32_bf16(afr[mt][0], c0, ac[mt], 0, 0, 0);
                ac[mt] = __builtin_amdgcn_mfma_f32_16x16x32_bf16(afr[mt][1], c1, ac[mt], 0, 0, 0);
            }

            // p = sum_o a_w[o] * rcp(exp2(2log2e*(t+b)) + 1);  score = 0.5*sum(aw) - p_total
            float p = 0.f;
#pragma unroll
            for (int mt = 0; mt < 4; ++mt)
#pragma unroll
                for (int r = 0; r < 4; ++r) {
                    const float m = fmaf(ac[mt][r], TWO_LOG2E, tb2[mt * 4 + r]);
                    const float e = __builtin_amdgcn_exp2f(m);
                    const float rc = __builtin_amdgcn_rcpf(e + 1.f);
                    p = fmaf(aw[mt * 4 + r], rc, p);
                }
            p += __shfl_xor(p, 16, 64);
            p += __shfl_xor(p, 32, 64);

            const int j = 16 * t + lane;
            if (lane < 16 && j >= i) srow[j] = half_sum_aw - p;
            c0 = n0; c1 = n1; t = tn;
        }
    }
}

// ---------------- finish: softmax (row+col reads) + agg + proj + BN + SELU ----------------
__global__ __launch_bounds__(256, 4)
void finish_kernel(const float* __restrict__ x,
                   const float* __restrict__ sc,
                   const float* __restrict__ W_p,
                   const float* __restrict__ b_p,
                   const float* __restrict__ W_q,
                   const float* __restrict__ b_q,
                   const float* __restrict__ gamma,
                   const float* __restrict__ beta,
                   const float* __restrict__ r_mean,
                   const float* __restrict__ r_var,
                   float* __restrict__ out)
{
    __shared__ float s_score[Nc];
    __shared__ float s_xi[Dc];
    __shared__ float s_red[4][Dc];
    __shared__ float s_tmp[4];

    const int blk = blockIdx.x;
    const int b   = blk & 1;
    const int i   = blk >> 1;
    const int tid  = threadIdx.x;
    const int lane = tid & 63;
    const int wid  = tid >> 6;

    const float* xb = x + (size_t)b * Nc * Dc;
    if (tid < Dc) s_xi[tid] = xb[i * Dc + tid];

    // gather scores: row-suffix (coalesced) + column-prefix (strided, L2/L3-hit)
    const float* srow = sc + ((size_t)b * Nc + i) * Nc;
    for (int j = i + tid; j < Nc; j += 256) s_score[j] = srow[j];
    for (int j = tid; j < i; j += 256)      s_score[j] = sc[((size_t)b * Nc + j) * Nc + i];
    __syncthreads();

    // softmax over 768
    float mx = -1e30f;
    for (int j = tid; j < Nc; j += 256) mx = fmaxf(mx, s_score[j]);
#pragma unroll
    for (int off = 32; off; off >>= 1)
        mx = fmaxf(mx, __shfl_xor(mx, off, 64));
    if (lane == 0) s_tmp[wid] = mx;
    __syncthreads();
    mx = fmaxf(fmaxf(s_tmp[0], s_tmp[1]), fmaxf(s_tmp[2], s_tmp[3]));
    __syncthreads();

    float sm = 0.f;
    for (int j = tid; j < Nc; j += 256) {
        const float e = __expf(s_score[j] - mx);
        s_score[j] = e;
        sm += e;
    }
#pragma unroll
    for (int off = 32; off; off >>= 1)
        sm += __shfl_xor(sm, off, 64);
    if (lane == 0) s_tmp[wid] = sm;
    __syncthreads();
    const float inv_sum = 1.f / (s_tmp[0] + s_tmp[1] + s_tmp[2] + s_tmp[3]);

    // agg[d] = sum_j att[j]*x[b,j,d]; lane = d
    float aggp = 0.f;
    const int j0 = wid * (Nc / 4), j1 = j0 + Nc / 4;
    for (int j = j0; j < j1; ++j)
        aggp = fmaf(s_score[j], xb[j * Dc + lane], aggp);
    s_red[wid][lane] = aggp;
    __syncthreads();

    if (wid == 0)
        s_red[0][lane] = (s_red[0][lane] + s_red[1][lane] +
                          s_red[2][lane] + s_red[3][lane]) * inv_sum;
    __syncthreads();

    if (wid == 0) {
        float y = b_p[lane] + b_q[lane];
#pragma unroll 8
        for (int d = 0; d < Dc; ++d) {
            y = fmaf(s_red[0][d], W_p[d * Dc + lane], y);
            y = fmaf(s_xi[d],     W_q[d * Dc + lane], y);
        }
        const float inv_std = rsqrtf(r_var[lane] + 1e-5f);
        y = (y - r_mean[lane]) * (gamma[lane] * inv_std) + beta[lane];
        const float kScale = 1.0507009873554805f;
        const float kAlpha = 1.6732632423543772f;
        y = y > 0.f ? kScale * y : kScale * kAlpha * (__expf(y) - 1.f);
        out[((size_t)b * Nc + i) * Dc + lane] = y;
    }
}

// ---------------- fallback: R2 mono-kernel (used only if ws too small) ----------------
__global__ __launch_bounds__(256, 4)
void mono_kernel(const float* __restrict__ x,
                 const float* __restrict__ W_att,
                 const float* __restrict__ b_att,
                 const float* __restrict__ a_w,
                 const float* __restrict__ W_p,
                 const float* __restrict__ b_p,
                 const float* __restrict__ W_q,
                 const float* __restrict__ b_q,
                 const float* __restrict__ gamma,
                 const float* __restrict__ beta,
                 const float* __restrict__ r_mean,
                 const float* __restrict__ r_var,
                 float* __restrict__ out)
{
    __shared__ short s_A[Dc * Dc];
    __shared__ float s_score[Nc];
    __shared__ float s_xi[Dc];
    __shared__ float s_red[4][Dc];
    __shared__ float s_tmp[4];

    const int bid = blockIdx.x;
    const int b   = bid / Nc;
    const int i   = bid - b * Nc;
    const int tid  = threadIdx.x;
    const int lane = tid & 63;
    const int wid  = tid >> 6;

    const float* xb = x + (size_t)b * Nc * Dc;
    if (tid < Dc) s_xi[tid] = xb[i * Dc + tid];
    __syncthreads();

    {
        const int d0 = wid * 16;
        float m0[16];
#pragma unroll
        for (int dd = 0; dd < 16; ++dd)
            m0[dd] = s_xi[d0 + dd] * W_att[(d0 + dd) * Dc + lane];
#pragma unroll
        for (int c8 = 0; c8 < 2; ++c8) {
            short8 v;
#pragma unroll
            for (int e = 0; e < 8; ++e) v[e] = fbf(m0[c8 * 8 + e]);
            const int c    = wid * 2 + c8;
            const int phys = c ^ (lane & 7);
            *(short8*)(&s_A[lane * Dc + phys * 8]) = v;
        }
    }

    float tb[16], aw[16];
#pragma unroll
    for (int mt = 0; mt < 4; ++mt)
#pragma unroll
        for (int r = 0; r < 4; ++r) {
            const int o = 16 * mt + 4 * (lane >> 4) + r;
            tb[mt * 4 + r] = 2.f * b_att[o];
            aw[mt * 4 + r] = a_w[o];
        }
    __syncthreads();

    short8 afr[4][2];
#pragma unroll
    for (int mt = 0; mt < 4; ++mt)
#pragma unroll
        for (int kt = 0; kt < 2; ++kt) {
            const int o    = 16 * mt + (lane & 15);
            const int c    = (lane >> 4) + 4 * kt;
            const int phys = c ^ (o & 7);
            afr[mt][kt] = *(const short8*)(&s_A[o * Dc + phys * 8]);
        }

    const int jbase = wid * 192;
    for (int t = 0; t < 12; ++t) {
        const int j0 = jbase + t * 16;
        const float* xr = xb + (size_t)(j0 + (lane & 15)) * Dc + (lane >> 4) * 8;
        const float4 v0 = *(const float4*)(xr);
        const float4 v1 = *(const float4*)(xr + 4);
        const float4 v2 = *(const float4*)(xr + 32);
        const float4 v3 = *(const float4*)(xr + 36);
        short8 bf0, bf1;
        bf0[0]=fbf(v0.x); bf0[1]=fbf(v0.y); bf0[2]=fbf(v0.z); bf0[3]=fbf(v0.w);
        bf0[4]=fbf(v1.x); bf0[5]=fbf(v1.y); bf0[6]=fbf(v1.z); bf0[7]=fbf(v1.w);
        bf1[0]=fbf(v2.x); bf1[1]=fbf(v2.y); bf1[2]=fbf(v2.z); bf1[3]=fbf(v2.w);
        bf1[4]=fbf(v3.x); bf1[5]=fbf(v3.y); bf1[6]=fbf(v3.z); bf1[7]=fbf(v3.w);

        f32x4 ac[4];
#pragma unroll
        for (int mt = 0; mt < 4; ++mt) {
            ac[mt] = (f32x4){0.f, 0.f, 0.f, 0.f};
            ac[mt] = __builtin_amdgcn_mfma_f32_16x16x32_bf16(afr[mt][0], bf0, ac[mt], 0, 0, 0);
            ac[mt] = __builtin_amdgcn_mfma_f32_16x16x32_bf16(afr[mt][1], bf1, ac[mt], 0, 0, 0);
        }

        float p = 0.f;
#pragma unroll
        for (int mt = 0; mt < 4; ++mt)
#pragma unroll
            for (int r = 0; r < 4; ++r) {
                const float e  = __expf(fmaf(ac[mt][r], 2.f, tb[mt * 4 + r]));
                const float th = 1.f - 2.f * __builtin_amdgcn_rcpf(e + 1.f);
                p = fmaf(th, aw[mt * 4 + r], p);
            }
        p += __shfl_xor(p, 16, 64);
        p += __shfl_xor(p, 32, 64);
        if (lane < 16) s_score[j0 + lane] = p * 0.5f;
    }
    __syncthreads();

    float mx = -1e30f;
    for (int j = tid; j < Nc; j += 256) mx = fmaxf(mx, s_score[j]);
#pragma unroll
    for (int off = 32; off; off >>= 1)
        mx = fmaxf(mx, __shfl_xor(mx, off, 64));
    if (lane == 0) s_tmp[wid] = mx;
    __syncthreads();
    mx = fmaxf(fmaxf(s_tmp[0], s_tmp[1]), fmaxf(s_tmp[2], s_tmp[3]));
    __syncthreads();

    float sm = 0.f;
    for (int j = tid; j < Nc; j += 256) {
        const float e = __expf(s_score[j] - mx);
        s_score[j] = e;
        sm += e;
    }
#pragma unroll
    for (int off = 32; off; off >>= 1)
        sm += __shfl_xor(sm, off, 64);
    if (lane == 0) s_tmp[wid] = sm;
    __syncthreads();
    const float inv_sum = 1.f / (s_tmp[0] + s_tmp[1] + s_tmp[2] + s_tmp[3]);

    float aggp = 0.f;
    const int j0 = wid * (Nc / 4), j1 = j0 + Nc / 4;
    for (int j = j0; j < j1; ++j)
        aggp = fmaf(s_score[j], xb[j * Dc + lane], aggp);
    s_red[wid][lane] = aggp;
    __syncthreads();

    if (wid == 0)
        s_red[0][lane] = (s_red[0][lane] + s_red[1][lane] +
                          s_red[2][lane] + s_red[3][lane]) * inv_sum;
    __syncthreads();

    if (wid == 0) {
        float y = b_p[lane] + b_q[lane];
#pragma unroll 8
        for (int d = 0; d < Dc; ++d) {
            y = fmaf(s_red[0][d], W_p[d * Dc + lane], y);
            y = fmaf(s_xi[d],     W_q[d * Dc + lane], y);
        }
        const float inv_std = rsqrtf(r_var[lane] + 1e-5f);
        y = (y - r_mean[lane]) * (gamma[lane] * inv_std) + beta[lane];
        const float kScale = 1.0507009873554805f;
        const float kAlpha = 1.6732632423543772f;
        y = y > 0.f ? kScale * y : kScale * kAlpha * (__expf(y) - 1.f);
        out[bid * Dc + lane] = y;
    }
}

extern "C" void kernel_launch(void* const* d_in, const int* in_sizes, int n_in,
                              void* d_out, int out_size, void* d_ws, size_t ws_size,
                              hipStream_t stream) {
    const float* x      = (const float*)d_in[0];
    const float* W_att  = (const float*)d_in[1];
    const float* b_att  = (const float*)d_in[2];
    const float* a_w    = (const float*)d_in[3];
    const float* W_p    = (const float*)d_in[4];
    const float* b_p    = (const float*)d_in[5];
    const float* W_q    = (const float*)d_in[6];
    const float* b_q    = (const float*)d_in[7];
    const float* gamma  = (const float*)d_in[8];
    const float* beta   = (const float*)d_in[9];
    const float* r_mean = (const float*)d_in[10];
    const float* r_var  = (const float*)d_in[11];
    float* out = (float*)d_out;

    constexpr size_t SC_OFF = 196608;                            // bf16 x: 2*768*64*2 B
    constexpr size_t NEED   = SC_OFF + (size_t)Bc * Nc * Nc * 4; // + f32 scores = 4,915,200 B

    if (ws_size >= NEED) {
        short* x_bf   = (short*)d_ws;
        float* scores = (float*)((char*)d_ws + SC_OFF);
        prep_kernel  <<<dim3((Bc * Nc * Dc / 4) / 256), dim3(256), 0, stream>>>(x, x_bf);
        scores_kernel<<<dim3(Bc * Nc), dim3(256), 0, stream>>>(x, x_bf, W_att, b_att, a_w, scores);
        finish_kernel<<<dim3(Bc * Nc), dim3(256), 0, stream>>>(x, scores, W_p, b_p, W_q, b_q,
                                                               gamma, beta, r_mean, r_var, out);
    } else {
        mono_kernel<<<dim3(Bc * Nc), dim3(256), 0, stream>>>(
            x, W_att, b_att, a_w, W_p, b_p, W_q, b_q,
            gamma, beta, r_mean, r_var, out);
    }
}